// Round 8
// baseline (71.582 us; speedup 1.0000x reference)
//
#include <hip/hip_runtime.h>
#include <hip/hip_bf16.h>
#include <math.h>

#define BB 8
#define FF 16
#define DD 256
#define HH 64
#define WW 64

typedef short bf16x8 __attribute__((ext_vector_type(8)));
typedef float f32x16 __attribute__((ext_vector_type(16)));

__device__ inline ushort f2bf(float f) {
    union { float f; unsigned u; } v; v.f = f;
    unsigned r = v.u + 0x7FFFu + ((v.u >> 16) & 1u);   // RNE
    return (ushort)(r >> 16);
}

// ---------------------------------------------------------------------------
// Kernel 0: cast x fp32 -> bf16, transpose to xb[b][r][c][i] (i innermost)
// ---------------------------------------------------------------------------
__global__ __launch_bounds__(256) void cast_x(
    const float* __restrict__ x,   // (B, D, 64, 64)
    ushort* __restrict__ xb)       // (B, 64, 64, D)
{
    __shared__ ushort ls[64][258];
    const int r = blockIdx.x, b = blockIdx.y, t = threadIdx.x;

    const int c4 = (t & 15) * 4;
    const int ig = t >> 4;
#pragma unroll
    for (int j = 0; j < 16; ++j) {
        const int i = ig * 16 + j;
        const float4 xv = *reinterpret_cast<const float4*>(
            x + (((size_t)(b * DD + i) * HH) + r) * WW + c4);
        ls[c4 + 0][i] = f2bf(xv.x);
        ls[c4 + 1][i] = f2bf(xv.y);
        ls[c4 + 2][i] = f2bf(xv.z);
        ls[c4 + 3][i] = f2bf(xv.w);
    }
    __syncthreads();

    const int i2 = t & 127;
    const int ch = t >> 7;
#pragma unroll
    for (int cl = 0; cl < 32; ++cl) {
        const int c = ch * 32 + cl;
        const unsigned u = (unsigned)ls[c][2 * i2] | ((unsigned)ls[c][2 * i2 + 1] << 16);
        *reinterpret_cast<unsigned*>(xb + (((size_t)(b * HH + r) * WW) + c) * DD + 2 * i2) = u;
    }
}

// ---------------------------------------------------------------------------
// Kernel 1: filters for ALL batches in one pass over bank_weight.
// Ak[b][tap][i/8][o][8] bf16  (coalesced A-fragment loads in conv)
// ---------------------------------------------------------------------------
__global__ __launch_bounds__(256) void prep_filter(
    const float* __restrict__ bank_request,   // (B, F)
    const float* __restrict__ style,          // (B, 1, D, 1, 1)
    const float* __restrict__ bank_weight,    // (F, D, D, 3, 3)
    ushort* __restrict__ Ak)                  // (B, 9, 32, 256, 8)
{
    const int o = blockIdx.x;
    const int i = threadIdx.x;

    __shared__ float wsm[BB][FF];
    __shared__ float red[4][BB];
    __shared__ float nrm[BB];

    if (i < BB) {
        float v[FF];
        float m = -1e30f;
#pragma unroll
        for (int f = 0; f < FF; ++f) {
            v[f] = bank_request[i * FF + f];
            m = fmaxf(m, v[f]);
        }
        float s = 0.f;
#pragma unroll
        for (int f = 0; f < FF; ++f) { v[f] = __expf(v[f] - m); s += v[f]; }
        const float inv = 1.0f / s;
#pragma unroll
        for (int f = 0; f < FF; ++f) wsm[i][f] = v[f] * inv;
    }
    __syncthreads();

    float acc9[BB][9];
#pragma unroll
    for (int b = 0; b < BB; ++b)
#pragma unroll
        for (int j = 0; j < 9; ++j) acc9[b][j] = 0.f;

    float pre[2][9];
#pragma unroll
    for (int s = 0; s < 2; ++s) {
        const float* p = bank_weight + ((size_t)(s * DD + o) * DD + i) * 9;
#pragma unroll
        for (int j = 0; j < 9; ++j) pre[s][j] = p[j];
    }
#pragma unroll
    for (int f = 0; f < FF; ++f) {
        const int sl = f & 1;
        float cur[9];
#pragma unroll
        for (int j = 0; j < 9; ++j) cur[j] = pre[sl][j];
        if (f + 2 < FF) {
            const float* p = bank_weight + ((size_t)((f + 2) * DD + o) * DD + i) * 9;
#pragma unroll
            for (int j = 0; j < 9; ++j) pre[sl][j] = p[j];
        }
#pragma unroll
        for (int b = 0; b < BB; ++b) {
            const float wf = wsm[b][f];
#pragma unroll
            for (int j = 0; j < 9; ++j) acc9[b][j] = fmaf(wf, cur[j], acc9[b][j]);
        }
    }

    float ss[BB];
#pragma unroll
    for (int b = 0; b < BB; ++b) {
        const float sm = 1.0f + style[b * DD + i];
        float t = 0.f;
#pragma unroll
        for (int j = 0; j < 9; ++j) {
            acc9[b][j] *= sm;
            t = fmaf(acc9[b][j], acc9[b][j], t);
        }
        ss[b] = t;
    }

    const int wave = i >> 6, lane = i & 63;
#pragma unroll
    for (int b = 0; b < BB; ++b) {
        float tv = ss[b];
#pragma unroll
        for (int off = 32; off > 0; off >>= 1) tv += __shfl_down(tv, off, 64);
        if (lane == 0) red[wave][b] = tv;
    }
    __syncthreads();
    if (i < BB)
        nrm[i] = rsqrtf(red[0][i] + red[1][i] + red[2][i] + red[3][i] + 1e-8f);
    __syncthreads();

    const int ib = i >> 3, e = i & 7;
#pragma unroll
    for (int b = 0; b < BB; ++b) {
        const float nb = nrm[b];
#pragma unroll
        for (int j = 0; j < 9; ++j) {
            const size_t idx = ((((size_t)(b * 9 + j) * 32 + ib) * DD) + o) * 8 + e;
            Ak[idx] = f2bf(acc9[b][j] * nb);
        }
    }
}

// ---------------------------------------------------------------------------
// Kernel 2: implicit-GEMM conv, MFMA 32x32x16 bf16.
// grid = 512 (XCD-swizzled), block = 256 (4 waves, 2o x 2r).
// Block tile: 128 o x (2 rows x 64 cols). Wave: 64 o x 64 px (fm=2, fn=2).
// Per-FLOP traffic: A(L2) 1/128, B(LDS) 1/128 -> LDS no longer co-bottleneck.
// ---------------------------------------------------------------------------
#define XROWS 4
#define XCELLS 66
#define XCELLB 80
#define XBUF (XROWS * XCELLS * XCELLB)   // 21120 B

__global__ __launch_bounds__(256, 2) void conv_mfma(
    const ushort* __restrict__ xb,   // (B, 64, 64, D) bf16
    const ushort* __restrict__ Ak,   // (B, 9, 32, 256, 8) bf16
    float* __restrict__ out)         // (B, D, 64, 64) fp32
{
    __shared__ __align__(16) char xs[2 * XBUF];   // 42240 B

    // wgid = (G&7) + 8*rg + 256*(G>>3), G = ot + 2*b  -> 2 (b,ot) groups per XCD
    const int wg = blockIdx.x;
    const int xcd = wg & 7;
    const int rem = wg >> 3;
    const int rg = rem & 31;
    const int Ghi = rem >> 5;            // 0..1
    const int G = xcd + 8 * Ghi;         // 0..15
    const int ot = G & 1, b = G >> 1;

    const int r0 = rg * 2, o0 = ot * 128;
    const int t = threadIdx.x;
    const int w = t >> 6, l = t & 63;
    const int wm = w >> 1;          // o half (0,1)
    const int wn = w & 1;           // row (0,1)
    const int l31 = l & 31, lhi = l >> 5;

    // staging: 4 rows * 66 cells * 4 q = 1056 16B chunks over 256 threads
    const ushort* sg_ptr[5];
    int sg_lds[5];
    bool sg_ok[5];
    bool sg_act[5];
#pragma unroll
    for (int s = 0; s < 5; ++s) {
        const int idx = t + s * 256;
        sg_act[s] = (s < 4) || (t < 32);
        const int row = idx / (XCELLS * 4);
        const int rem2 = idx - row * (XCELLS * 4);
        const int cell = rem2 >> 2;
        const int q = rem2 & 3;
        const int gr = r0 - 1 + row;
        const int gc = cell - 1;
        sg_ok[s] = sg_act[s] && ((unsigned)gr < 64u) && ((unsigned)gc < 64u);
        sg_ptr[s] = xb + (((size_t)(b * HH + (gr & 63)) * WW) + (gc & 63)) * DD + q * 8;
        sg_lds[s] = (row * XCELLS + cell) * XCELLB + q * 16;
    }

    f32x16 acc[2][2];
#pragma unroll
    for (int a = 0; a < 2; ++a)
#pragma unroll
        for (int c = 0; c < 2; ++c)
#pragma unroll
            for (int j = 0; j < 16; ++j) acc[a][c][j] = 0.f;

    // per-lane bases
    // A: lane row = l&31 (o), k-chunk = (l>>5)*8 (upper/lower half of K=16)
    const int obase = o0 + wm * 64 + l31;
    // B: lane col = l&31 (px), k-chunk = (l>>5)*8 -> +16B within 32B kstep slot
    const int bLane = l31 * XCELLB + lhi * 16;

    bf16x8 vr[5];
    bf16x8 aF[3][2], bF[2][2];

#define LDA(stp, sl, aB)  do {                                                 \
        const int tp_ = (stp) >> 1, ks_ = (stp) & 1;                           \
        const ushort* ap_ = (aB) + tp_ * 65536 + ks_ * 4096;                   \
        aF[sl][0] = *reinterpret_cast<const bf16x8*>(ap_);                     \
        aF[sl][1] = *reinterpret_cast<const bf16x8*>(ap_ + 256);               \
    } while (0)

#define LDB(stp, sl, bufc)  do {                                               \
        const int tp_ = (stp) >> 1, ks_ = (stp) & 1;                           \
        const int dr_ = tp_ / 3, dc_ = tp_ % 3;                                \
        const char* bb_ = (bufc) + ((wn + dr_) * XCELLS + dc_) * XCELLB        \
                          + ks_ * 32;                                          \
        bF[sl][0] = *reinterpret_cast<const bf16x8*>(bb_);                     \
        bF[sl][1] = *reinterpret_cast<const bf16x8*>(bb_ + 32 * XCELLB);       \
    } while (0)

    // prologue: stage chunk 0 into buffer 0
#pragma unroll
    for (int s = 0; s < 5; ++s) {
        if (sg_act[s]) {
            bf16x8 v = {0, 0, 0, 0, 0, 0, 0, 0};
            if (sg_ok[s]) v = *reinterpret_cast<const bf16x8*>(sg_ptr[s]);
            *reinterpret_cast<bf16x8*>(xs + sg_lds[s]) = v;
        }
    }
    __syncthreads();

    for (int kc = 0; kc < 8; ++kc) {
        const int cur = kc & 1;

        // issue next chunk's global loads (hide under 18-step compute)
        if (kc < 7) {
            const int ioff = (kc + 1) * 32;
#pragma unroll
            for (int s = 0; s < 5; ++s) {
                bf16x8 v = {0, 0, 0, 0, 0, 0, 0, 0};
                if (sg_ok[s]) v = *reinterpret_cast<const bf16x8*>(sg_ptr[s] + ioff);
                vr[s] = v;
            }
        }

        const char* bufc = xs + cur * XBUF + bLane;
        // Ak[b][tap][ib][o][8]; ib = kc*4 + ks*2 + lhi
        const ushort* aBase =
            Ak + ((((size_t)b * 9 * 32) + kc * 4 + lhi * 1) * DD + obase) * 8
               + 0;   // lhi folds into ib via +lhi*DD*8 below
        const ushort* aLane =
            Ak + ((((size_t)b * 9 * 32) + kc * 4 + lhi) * DD + obase) * 8;
        (void)aBase;

        LDA(0, 0, aLane);
        LDA(1, 1, aLane);
        LDB(0, 0, bufc);
#pragma unroll
        for (int stp = 0; stp < 18; ++stp) {
            const int as = stp % 3;
            if (stp + 2 < 18) LDA(stp + 2, (stp + 2) % 3, aLane);
            if (stp + 1 < 18) LDB(stp + 1, (stp + 1) & 1, bufc);
            const int bs = stp & 1;
            __builtin_amdgcn_s_setprio(1);
#pragma unroll
            for (int fm = 0; fm < 2; ++fm)
#pragma unroll
                for (int fn = 0; fn < 2; ++fn)
                    acc[fm][fn] = __builtin_amdgcn_mfma_f32_32x32x16_bf16(
                        aF[as][fm], bF[bs][fn], acc[fm][fn], 0, 0, 0);
            __builtin_amdgcn_s_setprio(0);
        }

        // write staged chunk to the other buffer
        if (kc < 7) {
            char* dstb = xs + (cur ^ 1) * XBUF;
#pragma unroll
            for (int s = 0; s < 5; ++s)
                if (sg_act[s]) *reinterpret_cast<bf16x8*>(dstb + sg_lds[s]) = vr[s];
        }
        __syncthreads();
    }
#undef LDA
#undef LDB

    // epilogue: C/D 32x32 layout col=lane&31 (px), row=(reg&3)+8*(reg>>2)+4*(lane>>5)
    const int r_out = r0 + wn;
#pragma unroll
    for (int fm = 0; fm < 2; ++fm) {
#pragma unroll
        for (int fn = 0; fn < 2; ++fn) {
            const int cc = fn * 32 + l31;
#pragma unroll
            for (int reg = 0; reg < 16; ++reg) {
                const int oo = o0 + wm * 64 + fm * 32
                             + (reg & 3) + 8 * (reg >> 2) + 4 * lhi;
                out[(((size_t)(b * DD + oo) * HH) + r_out) * WW + cc] =
                    acc[fm][fn][reg];
            }
        }
    }
}

extern "C" void kernel_launch(void* const* d_in, const int* in_sizes, int n_in,
                              void* d_out, int out_size, void* d_ws, size_t ws_size,
                              hipStream_t stream) {
    const float* x            = (const float*)d_in[0];  // (8,256,64,64)
    const float* bank_request = (const float*)d_in[1];  // (8,16)
    const float* style        = (const float*)d_in[2];  // (8,1,256,1,1)
    const float* bank_weight  = (const float*)d_in[3];  // (16,256,256,3,3)
    float* out = (float*)d_out;                         // (8,256,64,64)

    ushort* Ak = (ushort*)d_ws;                         // 8*9*32*256*8 elems
    ushort* xb = Ak + (size_t)8 * 9 * 32 * 256 * 8;     // 8*64*64*256 elems

    cast_x<<<dim3(HH, BB), 256, 0, stream>>>(x, xb);
    prep_filter<<<dim3(DD), 256, 0, stream>>>(bank_request, style, bank_weight, Ak);
    conv_mfma<<<dim3(512), 256, 0, stream>>>(xb, Ak, out);
}

// Round 9
// 70.973 us; speedup vs baseline: 1.0086x; 1.0086x over previous
//
#include <hip/hip_runtime.h>
#include <hip/hip_bf16.h>
#include <math.h>

#define BB 8
#define FF 16
#define DD 256
#define HH 64
#define WW 64

typedef short bf16x8 __attribute__((ext_vector_type(8)));
typedef float f32x16 __attribute__((ext_vector_type(16)));

__device__ inline ushort f2bf(float f) {
    union { float f; unsigned u; } v; v.f = f;
    unsigned r = v.u + 0x7FFFu + ((v.u >> 16) & 1u);   // RNE
    return (ushort)(r >> 16);
}

// ---------------------------------------------------------------------------
// Kernel 0: cast x fp32 -> bf16, transpose to xb[b][r][c][i] (i innermost)
// ---------------------------------------------------------------------------
__global__ __launch_bounds__(256) void cast_x(
    const float* __restrict__ x,   // (B, D, 64, 64)
    ushort* __restrict__ xb)       // (B, 64, 64, D)
{
    __shared__ ushort ls[64][258];
    const int r = blockIdx.x, b = blockIdx.y, t = threadIdx.x;

    const int c4 = (t & 15) * 4;
    const int ig = t >> 4;
#pragma unroll
    for (int j = 0; j < 16; ++j) {
        const int i = ig * 16 + j;
        const float4 xv = *reinterpret_cast<const float4*>(
            x + (((size_t)(b * DD + i) * HH) + r) * WW + c4);
        ls[c4 + 0][i] = f2bf(xv.x);
        ls[c4 + 1][i] = f2bf(xv.y);
        ls[c4 + 2][i] = f2bf(xv.z);
        ls[c4 + 3][i] = f2bf(xv.w);
    }
    __syncthreads();

    const int i2 = t & 127;
    const int ch = t >> 7;
#pragma unroll
    for (int cl = 0; cl < 32; ++cl) {
        const int c = ch * 32 + cl;
        const unsigned u = (unsigned)ls[c][2 * i2] | ((unsigned)ls[c][2 * i2 + 1] << 16);
        *reinterpret_cast<unsigned*>(xb + (((size_t)(b * HH + r) * WW) + c) * DD + 2 * i2) = u;
    }
}

// ---------------------------------------------------------------------------
// Kernel 1: filters for ALL batches in one pass over bank_weight.
// Ak[b][tap][i/8][o][8] bf16  (coalesced A-fragment loads in conv)
// ---------------------------------------------------------------------------
__global__ __launch_bounds__(256) void prep_filter(
    const float* __restrict__ bank_request,   // (B, F)
    const float* __restrict__ style,          // (B, 1, D, 1, 1)
    const float* __restrict__ bank_weight,    // (F, D, D, 3, 3)
    ushort* __restrict__ Ak)                  // (B, 9, 32, 256, 8)
{
    const int o = blockIdx.x;
    const int i = threadIdx.x;

    __shared__ float wsm[BB][FF];
    __shared__ float red[4][BB];
    __shared__ float nrm[BB];

    if (i < BB) {
        float v[FF];
        float m = -1e30f;
#pragma unroll
        for (int f = 0; f < FF; ++f) {
            v[f] = bank_request[i * FF + f];
            m = fmaxf(m, v[f]);
        }
        float s = 0.f;
#pragma unroll
        for (int f = 0; f < FF; ++f) { v[f] = __expf(v[f] - m); s += v[f]; }
        const float inv = 1.0f / s;
#pragma unroll
        for (int f = 0; f < FF; ++f) wsm[i][f] = v[f] * inv;
    }
    __syncthreads();

    float acc9[BB][9];
#pragma unroll
    for (int b = 0; b < BB; ++b)
#pragma unroll
        for (int j = 0; j < 9; ++j) acc9[b][j] = 0.f;

    float pre[2][9];
#pragma unroll
    for (int s = 0; s < 2; ++s) {
        const float* p = bank_weight + ((size_t)(s * DD + o) * DD + i) * 9;
#pragma unroll
        for (int j = 0; j < 9; ++j) pre[s][j] = p[j];
    }
#pragma unroll
    for (int f = 0; f < FF; ++f) {
        const int sl = f & 1;
        float cur[9];
#pragma unroll
        for (int j = 0; j < 9; ++j) cur[j] = pre[sl][j];
        if (f + 2 < FF) {
            const float* p = bank_weight + ((size_t)((f + 2) * DD + o) * DD + i) * 9;
#pragma unroll
            for (int j = 0; j < 9; ++j) pre[sl][j] = p[j];
        }
#pragma unroll
        for (int b = 0; b < BB; ++b) {
            const float wf = wsm[b][f];
#pragma unroll
            for (int j = 0; j < 9; ++j) acc9[b][j] = fmaf(wf, cur[j], acc9[b][j]);
        }
    }

    float ss[BB];
#pragma unroll
    for (int b = 0; b < BB; ++b) {
        const float sm = 1.0f + style[b * DD + i];
        float t = 0.f;
#pragma unroll
        for (int j = 0; j < 9; ++j) {
            acc9[b][j] *= sm;
            t = fmaf(acc9[b][j], acc9[b][j], t);
        }
        ss[b] = t;
    }

    const int wave = i >> 6, lane = i & 63;
#pragma unroll
    for (int b = 0; b < BB; ++b) {
        float tv = ss[b];
#pragma unroll
        for (int off = 32; off > 0; off >>= 1) tv += __shfl_down(tv, off, 64);
        if (lane == 0) red[wave][b] = tv;
    }
    __syncthreads();
    if (i < BB)
        nrm[i] = rsqrtf(red[0][i] + red[1][i] + red[2][i] + red[3][i] + 1e-8f);
    __syncthreads();

    const int ib = i >> 3, e = i & 7;
#pragma unroll
    for (int b = 0; b < BB; ++b) {
        const float nb = nrm[b];
#pragma unroll
        for (int j = 0; j < 9; ++j) {
            const size_t idx = ((((size_t)(b * 9 + j) * 32 + ib) * DD) + o) * 8 + e;
            Ak[idx] = f2bf(acc9[b][j] * nb);
        }
    }
}

// ---------------------------------------------------------------------------
// Kernel 2: implicit-GEMM conv, MFMA 32x32x16 bf16.
// grid = 512 (XCD-swizzled), block = 256 (4 waves, 2o x 2r).
// Block tile: 128 o x (2 rows x 64 cols). Wave: 64 o x 64 px (fm=2, fn=2).
// Deep prefetch: A 6-slot (5 steps ahead ~ 160cyc >= L2 latency),
//                B 4-slot (3 steps ahead ~ 96cyc >= LDS latency).
// ---------------------------------------------------------------------------
#define XROWS 4
#define XCELLS 66
#define XCELLB 80
#define XBUF (XROWS * XCELLS * XCELLB)   // 21120 B

__global__ __launch_bounds__(256, 2) void conv_mfma(
    const ushort* __restrict__ xb,   // (B, 64, 64, D) bf16
    const ushort* __restrict__ Ak,   // (B, 9, 32, 256, 8) bf16
    float* __restrict__ out)         // (B, D, 64, 64) fp32
{
    __shared__ __align__(16) char xs[2 * XBUF];   // 42240 B

    // wgid = (G&7) + 8*rg + 256*(G>>3), G = ot + 2*b  -> 2 (b,ot) groups per XCD
    const int wg = blockIdx.x;
    const int xcd = wg & 7;
    const int rem = wg >> 3;
    const int rg = rem & 31;
    const int Ghi = rem >> 5;            // 0..1
    const int G = xcd + 8 * Ghi;         // 0..15
    const int ot = G & 1, b = G >> 1;

    const int r0 = rg * 2, o0 = ot * 128;
    const int t = threadIdx.x;
    const int w = t >> 6, l = t & 63;
    const int wm = w >> 1;          // o half (0,1)
    const int wn = w & 1;           // row (0,1)
    const int l31 = l & 31, lhi = l >> 5;

    // staging: 4 rows * 66 cells * 4 q = 1056 16B chunks over 256 threads
    const ushort* sg_ptr[5];
    int sg_lds[5];
    bool sg_ok[5];
    bool sg_act[5];
#pragma unroll
    for (int s = 0; s < 5; ++s) {
        const int idx = t + s * 256;
        sg_act[s] = (s < 4) || (t < 32);
        const int row = idx / (XCELLS * 4);
        const int rem2 = idx - row * (XCELLS * 4);
        const int cell = rem2 >> 2;
        const int q = rem2 & 3;
        const int gr = r0 - 1 + row;
        const int gc = cell - 1;
        sg_ok[s] = sg_act[s] && ((unsigned)gr < 64u) && ((unsigned)gc < 64u);
        sg_ptr[s] = xb + (((size_t)(b * HH + (gr & 63)) * WW) + (gc & 63)) * DD + q * 8;
        sg_lds[s] = (row * XCELLS + cell) * XCELLB + q * 16;
    }

    f32x16 acc[2][2];
#pragma unroll
    for (int a = 0; a < 2; ++a)
#pragma unroll
        for (int c = 0; c < 2; ++c)
#pragma unroll
            for (int j = 0; j < 16; ++j) acc[a][c][j] = 0.f;

    // A: lane row = l&31 (o), k-chunk = (l>>5)*8
    const int obase = o0 + wm * 64 + l31;
    // B: lane col = l&31 (px), k-chunk = (l>>5)*8
    const int bLane = l31 * XCELLB + lhi * 16;

    bf16x8 vr[5];
    bf16x8 aF[6][2], bF[4][2];

#define LDA(stp, sl, aB)  do {                                                 \
        const int tp_ = (stp) >> 1, ks_ = (stp) & 1;                           \
        const ushort* ap_ = (aB) + tp_ * 65536 + ks_ * 4096;                   \
        aF[sl][0] = *reinterpret_cast<const bf16x8*>(ap_);                     \
        aF[sl][1] = *reinterpret_cast<const bf16x8*>(ap_ + 256);               \
    } while (0)

#define LDB(stp, sl, bufc)  do {                                               \
        const int tp_ = (stp) >> 1, ks_ = (stp) & 1;                           \
        const int dr_ = tp_ / 3, dc_ = tp_ % 3;                                \
        const char* bb_ = (bufc) + ((wn + dr_) * XCELLS + dc_) * XCELLB        \
                          + ks_ * 32;                                          \
        bF[sl][0] = *reinterpret_cast<const bf16x8*>(bb_);                     \
        bF[sl][1] = *reinterpret_cast<const bf16x8*>(bb_ + 32 * XCELLB);       \
    } while (0)

    // prologue: stage chunk 0 into buffer 0
#pragma unroll
    for (int s = 0; s < 5; ++s) {
        if (sg_act[s]) {
            bf16x8 v = {0, 0, 0, 0, 0, 0, 0, 0};
            if (sg_ok[s]) v = *reinterpret_cast<const bf16x8*>(sg_ptr[s]);
            *reinterpret_cast<bf16x8*>(xs + sg_lds[s]) = v;
        }
    }
    __syncthreads();

    for (int kc = 0; kc < 8; ++kc) {
        const int cur = kc & 1;

        // issue next chunk's global loads (hide under 18-step compute)
        if (kc < 7) {
            const int ioff = (kc + 1) * 32;
#pragma unroll
            for (int s = 0; s < 5; ++s) {
                bf16x8 v = {0, 0, 0, 0, 0, 0, 0, 0};
                if (sg_ok[s]) v = *reinterpret_cast<const bf16x8*>(sg_ptr[s] + ioff);
                vr[s] = v;
            }
        }

        const char* bufc = xs + cur * XBUF + bLane;
        // Ak[b][tap][ib][o][8]; ib = kc*4 + ks*2 + lhi
        const ushort* aLane =
            Ak + ((((size_t)b * 9 * 32) + kc * 4 + lhi) * DD + obase) * 8;

        // fill pipelines: A 5 ahead, B 3 ahead
        LDA(0, 0, aLane); LDA(1, 1, aLane); LDA(2, 2, aLane);
        LDA(3, 3, aLane); LDA(4, 4, aLane);
        LDB(0, 0, bufc);  LDB(1, 1, bufc);  LDB(2, 2, bufc);
#pragma unroll
        for (int stp = 0; stp < 18; ++stp) {
            const int as = stp % 6;
            const int bs = stp & 3;
            if (stp + 5 < 18) LDA(stp + 5, (stp + 5) % 6, aLane);
            if (stp + 3 < 18) LDB(stp + 3, (stp + 3) & 3, bufc);
            __builtin_amdgcn_s_setprio(1);
#pragma unroll
            for (int fm = 0; fm < 2; ++fm)
#pragma unroll
                for (int fn = 0; fn < 2; ++fn)
                    acc[fm][fn] = __builtin_amdgcn_mfma_f32_32x32x16_bf16(
                        aF[as][fm], bF[bs][fn], acc[fm][fn], 0, 0, 0);
            __builtin_amdgcn_s_setprio(0);
        }

        // write staged chunk to the other buffer
        if (kc < 7) {
            char* dstb = xs + (cur ^ 1) * XBUF;
#pragma unroll
            for (int s = 0; s < 5; ++s)
                if (sg_act[s]) *reinterpret_cast<bf16x8*>(dstb + sg_lds[s]) = vr[s];
        }
        __syncthreads();
    }
#undef LDA
#undef LDB

    // epilogue: C/D 32x32 layout col=lane&31 (px), row=(reg&3)+8*(reg>>2)+4*(lane>>5)
    const int r_out = r0 + wn;
#pragma unroll
    for (int fm = 0; fm < 2; ++fm) {
#pragma unroll
        for (int fn = 0; fn < 2; ++fn) {
            const int cc = fn * 32 + l31;
#pragma unroll
            for (int reg = 0; reg < 16; ++reg) {
                const int oo = o0 + wm * 64 + fm * 32
                             + (reg & 3) + 8 * (reg >> 2) + 4 * lhi;
                out[(((size_t)(b * DD + oo) * HH) + r_out) * WW + cc] =
                    acc[fm][fn][reg];
            }
        }
    }
}

extern "C" void kernel_launch(void* const* d_in, const int* in_sizes, int n_in,
                              void* d_out, int out_size, void* d_ws, size_t ws_size,
                              hipStream_t stream) {
    const float* x            = (const float*)d_in[0];  // (8,256,64,64)
    const float* bank_request = (const float*)d_in[1];  // (8,16)
    const float* style        = (const float*)d_in[2];  // (8,1,256,1,1)
    const float* bank_weight  = (const float*)d_in[3];  // (16,256,256,3,3)
    float* out = (float*)d_out;                         // (8,256,64,64)

    ushort* Ak = (ushort*)d_ws;                         // 8*9*32*256*8 elems
    ushort* xb = Ak + (size_t)8 * 9 * 32 * 256 * 8;     // 8*64*64*256 elems

    cast_x<<<dim3(HH, BB), 256, 0, stream>>>(x, xb);
    prep_filter<<<dim3(DD), 256, 0, stream>>>(bank_request, style, bank_weight, Ak);
    conv_mfma<<<dim3(512), 256, 0, stream>>>(xb, Ak, out);
}